// Round 3
// baseline (609.803 us; speedup 1.0000x reference)
//
#include <hip/hip_runtime.h>

#define S_LEN 512
#define BATCH 64
#define HDIM  1024
#define TWOH  2048
#define EMB   512
#define KDIM  2560      // 2H + EMB
#define VOUT  32000

// ws layout (float offsets)
#define WS_HB    0
#define WS_MS    64
#define WS_CTX   2112
#define WS_RNNT  (WS_CTX + 64*16*2048)       // 2,099,264
#define WS_HIDT  (WS_RNNT + KDIM*64)         // 2,263,104
#define WS_HT    (WS_HIDT + HDIM*64)         // 2,328,640

__device__ __forceinline__ float sigmoidf_(float x) { return 1.f/(1.f+__expf(-x)); }

// K0: hb[b] = hidden[b,:] . energy_W[0:H] + energy_b
__global__ __launch_bounds__(64) void k_hb(const float* __restrict__ hidden,
                                           const float* __restrict__ eW,
                                           const float* __restrict__ eb,
                                           float* __restrict__ ws_hb) {
  int b = blockIdx.x, lane = threadIdx.x;
  float acc = 0.f;
  for (int k = lane; k < HDIM; k += 64) acc += hidden[b*HDIM + k] * eW[k];
#pragma unroll
  for (int st = 32; st >= 1; st >>= 1) acc += __shfl_xor(acc, st, 64);
  if (lane == 0) ws_hb[b] = acc + eb[0];
}

// K1: per (b, chunk of 32 s): partial online-softmax context.
// wave handles 8 s; lane owns d = 4*lane + 256*k, k=0..7.
__global__ __launch_bounds__(256) void k_attn(const float* __restrict__ enc,
                                              const float* __restrict__ eW,
                                              const float* __restrict__ ws_hb,
                                              float* __restrict__ ws_ms,
                                              float* __restrict__ ws_ctx) {
  __shared__ float lds_ms[4][2];
  __shared__ float lds_ctx[4][2048];
  const int lane  = threadIdx.x & 63;
  const int wave  = threadIdx.x >> 6;
  const int chunk = blockIdx.x;   // 0..15
  const int b     = blockIdx.y;   // 0..63

  float4 w4[8];
#pragma unroll
  for (int k = 0; k < 8; ++k)
    w4[k] = *reinterpret_cast<const float4*>(eW + HDIM + 4*lane + 256*k);
  const float hb = ws_hb[b];

  const int s0 = chunk*32 + wave*8;
  const float* base = enc + ((size_t)(s0*BATCH + b))*TWOH + 4*lane;

  // phase A: 8 energies, 64 loads in flight
  float e[8];
#pragma unroll
  for (int i = 0; i < 8; ++i) {
    const float* p = base + (size_t)i*BATCH*TWOH;
    float a0 = 0.f, a1 = 0.f;
#pragma unroll
    for (int k = 0; k < 8; k += 2) {
      float4 v0 = *reinterpret_cast<const float4*>(p + 256*k);
      float4 v1 = *reinterpret_cast<const float4*>(p + 256*(k+1));
      a0 += v0.x*w4[k].x + v0.y*w4[k].y + v0.z*w4[k].z + v0.w*w4[k].w;
      a1 += v1.x*w4[k+1].x + v1.y*w4[k+1].y + v1.z*w4[k+1].z + v1.w*w4[k+1].w;
    }
    e[i] = a0 + a1;
  }
#pragma unroll
  for (int st = 1; st < 64; st <<= 1) {
#pragma unroll
    for (int i = 0; i < 8; ++i) e[i] += __shfl_xor(e[i], st, 64);
  }
  float m = 0.f;  // relu makes all e >= 0
#pragma unroll
  for (int i = 0; i < 8; ++i) { e[i] = fmaxf(e[i] + hb, 0.f); m = fmaxf(m, e[i]); }
  float pr[8], psum = 0.f;
#pragma unroll
  for (int i = 0; i < 8; ++i) { pr[i] = __expf(e[i] - m); psum += pr[i]; }

  // phase B: weighted sum, re-read (L2-hot)
  float4 ctx[8];
#pragma unroll
  for (int k = 0; k < 8; ++k) ctx[k] = make_float4(0.f, 0.f, 0.f, 0.f);
#pragma unroll
  for (int i = 0; i < 8; ++i) {
    const float* p = base + (size_t)i*BATCH*TWOH;
    const float pi = pr[i];
#pragma unroll
    for (int k = 0; k < 8; ++k) {
      float4 v = *reinterpret_cast<const float4*>(p + 256*k);
      ctx[k].x = fmaf(pi, v.x, ctx[k].x);
      ctx[k].y = fmaf(pi, v.y, ctx[k].y);
      ctx[k].z = fmaf(pi, v.z, ctx[k].z);
      ctx[k].w = fmaf(pi, v.w, ctx[k].w);
    }
  }

  // combine 4 waves in LDS
  if (lane == 0) { lds_ms[wave][0] = m; lds_ms[wave][1] = psum; }
  __syncthreads();
  const float M = fmaxf(fmaxf(lds_ms[0][0], lds_ms[1][0]),
                        fmaxf(lds_ms[2][0], lds_ms[3][0]));
  const float wsc = __expf(m - M);
  float ssum = 0.f;
#pragma unroll
  for (int w = 0; w < 4; ++w) ssum += __expf(lds_ms[w][0] - M) * lds_ms[w][1];
#pragma unroll
  for (int k = 0; k < 8; ++k) {
    float4 c = ctx[k];
    c.x *= wsc; c.y *= wsc; c.z *= wsc; c.w *= wsc;
    *reinterpret_cast<float4*>(&lds_ctx[wave][4*lane + 256*k]) = c;
  }
  __syncthreads();
  float* outp = ws_ctx + ((size_t)b*16 + chunk)*TWOH;
  for (int d = threadIdx.x; d < TWOH; d += 256)
    outp[d] = lds_ctx[0][d] + lds_ctx[1][d] + lds_ctx[2][d] + lds_ctx[3][d];
  if (threadIdx.x == 0) {
    ws_ms[((size_t)b*16 + chunk)*2]     = M;
    ws_ms[((size_t)b*16 + chunk)*2 + 1] = ssum;
  }
}

// K2: combine 16 chunk-partials per b; build transposed rnn input + hidden
__global__ __launch_bounds__(256) void k_combine(const float* __restrict__ ws_ms,
                                                 const float* __restrict__ ws_ctx,
                                                 const float* __restrict__ hidden,
                                                 const float* __restrict__ emb_table,
                                                 const int* __restrict__ x,
                                                 float* __restrict__ ws_rnnT,
                                                 float* __restrict__ ws_hidT) {
  const int b = blockIdx.x;
  float mc[16], sc[16];
#pragma unroll
  for (int c = 0; c < 16; ++c) {
    mc[c] = ws_ms[(b*16 + c)*2];
    sc[c] = ws_ms[(b*16 + c)*2 + 1];
  }
  float M = mc[0];
#pragma unroll
  for (int c = 1; c < 16; ++c) M = fmaxf(M, mc[c]);
  float wc[16], Ssum = 0.f;
#pragma unroll
  for (int c = 0; c < 16; ++c) { wc[c] = __expf(mc[c] - M); Ssum += wc[c]*sc[c]; }
  const float inv = 1.f / Ssum;
  for (int d = threadIdx.x; d < TWOH; d += 256) {
    float a = 0.f;
#pragma unroll
    for (int c = 0; c < 16; ++c) a += wc[c] * ws_ctx[((size_t)b*16 + c)*TWOH + d];
    ws_rnnT[(size_t)d*64 + b] = a * inv;
  }
  const int xb = x[b];
  for (int e = threadIdx.x; e < EMB; e += 256)
    ws_rnnT[(size_t)(TWOH + e)*64 + b] = emb_table[(size_t)xb*EMB + e];
  for (int k = threadIdx.x; k < HDIM; k += 256)
    ws_hidT[(size_t)k*64 + b] = hidden[b*HDIM + k];
}

// K3: gates + LSTM. Block handles 4 h-indices x 4 gates; wave = gate, lanes = b.
__global__ __launch_bounds__(256) void k_gates(const float* __restrict__ ws_rnnT,
                                               const float* __restrict__ ws_hidT,
                                               const float* __restrict__ W_ih,
                                               const float* __restrict__ W_hh,
                                               const float* __restrict__ b_ih,
                                               const float* __restrict__ b_hh,
                                               const float* __restrict__ cell,
                                               float* __restrict__ out_h,
                                               float* __restrict__ out_c,
                                               float* __restrict__ ws_hT) {
  __shared__ float lds_in[128*64];
  __shared__ float lds_g[4][4][64];
  const int lane = threadIdx.x & 63;
  const int wave = threadIdx.x >> 6;
  const int h0 = blockIdx.x * 4;

  float acc[4];
  const float* wih[4];
  const float* whh[4];
#pragma unroll
  for (int q = 0; q < 4; ++q) {
    const int j = wave*HDIM + h0 + q;
    acc[q] = b_ih[j] + b_hh[j];
    wih[q] = W_ih + (size_t)j*KDIM;
    whh[q] = W_hh + (size_t)j*HDIM;
  }

#define FMA4(A, WV) A = fmaf(v0, WV.x, A); A = fmaf(v1, WV.y, A); \
                    A = fmaf(v2, WV.z, A); A = fmaf(v3, WV.w, A);

  for (int c = 0; c < 28; ++c) {
    const int k0 = c * 128;
    const float* src = (k0 < KDIM) ? (ws_rnnT + (size_t)k0*64)
                                   : (ws_hidT + (size_t)(k0 - KDIM)*64);
    const float4* s4 = reinterpret_cast<const float4*>(src);
    float4* l4 = reinterpret_cast<float4*>(lds_in);
    for (int i = threadIdx.x; i < 2048; i += 256) l4[i] = s4[i];
    __syncthreads();
    if (k0 < KDIM) {
      for (int kk = 0; kk < 128; kk += 4) {
        const float4 wv0 = *reinterpret_cast<const float4*>(wih[0] + k0 + kk);
        const float4 wv1 = *reinterpret_cast<const float4*>(wih[1] + k0 + kk);
        const float4 wv2 = *reinterpret_cast<const float4*>(wih[2] + k0 + kk);
        const float4 wv3 = *reinterpret_cast<const float4*>(wih[3] + k0 + kk);
        const float v0 = lds_in[(kk+0)*64 + lane];
        const float v1 = lds_in[(kk+1)*64 + lane];
        const float v2 = lds_in[(kk+2)*64 + lane];
        const float v3 = lds_in[(kk+3)*64 + lane];
        FMA4(acc[0], wv0) FMA4(acc[1], wv1) FMA4(acc[2], wv2) FMA4(acc[3], wv3)
      }
    } else {
      const int kh = k0 - KDIM;
      for (int kk = 0; kk < 128; kk += 4) {
        const float4 wv0 = *reinterpret_cast<const float4*>(whh[0] + kh + kk);
        const float4 wv1 = *reinterpret_cast<const float4*>(whh[1] + kh + kk);
        const float4 wv2 = *reinterpret_cast<const float4*>(whh[2] + kh + kk);
        const float4 wv3 = *reinterpret_cast<const float4*>(whh[3] + kh + kk);
        const float v0 = lds_in[(kk+0)*64 + lane];
        const float v1 = lds_in[(kk+1)*64 + lane];
        const float v2 = lds_in[(kk+2)*64 + lane];
        const float v3 = lds_in[(kk+3)*64 + lane];
        FMA4(acc[0], wv0) FMA4(acc[1], wv1) FMA4(acc[2], wv2) FMA4(acc[3], wv3)
      }
    }
    __syncthreads();
  }
#undef FMA4

#pragma unroll
  for (int q = 0; q < 4; ++q) lds_g[wave][q][lane] = acc[q];
  __syncthreads();
  const int hl = wave;
  const int b = lane;
  const float iv = sigmoidf_(lds_g[0][hl][b]);
  const float fv = sigmoidf_(lds_g[1][hl][b]);
  const float gv = tanhf(lds_g[2][hl][b]);
  const float ov = sigmoidf_(lds_g[3][hl][b]);
  const int h = h0 + hl;
  const float cold = cell[b*HDIM + h];
  const float cn = fmaf(fv, cold, iv*gv);
  const float hn = ov * tanhf(cn);
  out_h[b*HDIM + h] = hn;
  out_c[b*HDIM + h] = cn;
  ws_hT[(size_t)h*64 + b] = hn;
}

// K4: preds[b,o] = h_new[b,:] . fc_W[o,:] + fc_b[o].  Wave = 16 o rows, lanes = b.
__global__ __launch_bounds__(256) void k_fc(const float* __restrict__ ws_hT,
                                            const float* __restrict__ fc_W,
                                            const float* __restrict__ fc_b,
                                            float* __restrict__ preds) {
  const int lane = threadIdx.x & 63;
  const int wave = threadIdx.x >> 6;
  const int ob = (blockIdx.x*4 + wave)*16;
  float acc[16];
#pragma unroll
  for (int r = 0; r < 16; ++r) acc[r] = fc_b[ob + r];
  const float* w0 = fc_W + (size_t)ob*HDIM;
  for (int k = 0; k < HDIM; k += 4) {
    const float v0 = ws_hT[(k+0)*64 + lane];
    const float v1 = ws_hT[(k+1)*64 + lane];
    const float v2 = ws_hT[(k+2)*64 + lane];
    const float v3 = ws_hT[(k+3)*64 + lane];
#pragma unroll
    for (int r = 0; r < 16; ++r) {
      const float4 wv = *reinterpret_cast<const float4*>(w0 + (size_t)r*HDIM + k);
      acc[r] = fmaf(v0, wv.x, acc[r]);
      acc[r] = fmaf(v1, wv.y, acc[r]);
      acc[r] = fmaf(v2, wv.z, acc[r]);
      acc[r] = fmaf(v3, wv.w, acc[r]);
    }
  }
  float* p = preds + (size_t)lane*VOUT + ob;
#pragma unroll
  for (int r4 = 0; r4 < 16; r4 += 4) {
    float4 st = make_float4(acc[r4], acc[r4+1], acc[r4+2], acc[r4+3]);
    *reinterpret_cast<float4*>(p + r4) = st;
  }
}

extern "C" void kernel_launch(void* const* d_in, const int* in_sizes, int n_in,
                              void* d_out, int out_size, void* d_ws, size_t ws_size,
                              hipStream_t stream) {
  const int*   x      = (const int*)  d_in[0];
  const float* enc    = (const float*)d_in[1];
  const float* hidden = (const float*)d_in[2];
  const float* cell   = (const float*)d_in[3];
  const float* embt   = (const float*)d_in[4];
  const float* eW     = (const float*)d_in[5];
  const float* eb     = (const float*)d_in[6];
  const float* W_ih   = (const float*)d_in[7];
  const float* W_hh   = (const float*)d_in[8];
  const float* b_ih   = (const float*)d_in[9];
  const float* b_hh   = (const float*)d_in[10];
  const float* fc_W   = (const float*)d_in[11];
  const float* fc_b   = (const float*)d_in[12];

  float* out   = (float*)d_out;
  float* preds = out;                              // 64*32000
  float* out_h = out + (size_t)BATCH*VOUT;         // 64*1024
  float* out_c = out_h + BATCH*HDIM;               // 64*1024
  float* ws    = (float*)d_ws;

  k_hb<<<64, 64, 0, stream>>>(hidden, eW, eb, ws + WS_HB);
  k_attn<<<dim3(16, 64), 256, 0, stream>>>(enc, eW, ws + WS_HB, ws + WS_MS, ws + WS_CTX);
  k_combine<<<64, 256, 0, stream>>>(ws + WS_MS, ws + WS_CTX, hidden, embt, x,
                                    ws + WS_RNNT, ws + WS_HIDT);
  k_gates<<<256, 256, 0, stream>>>(ws + WS_RNNT, ws + WS_HIDT, W_ih, W_hh,
                                   b_ih, b_hh, cell, out_h, out_c, ws + WS_HT);
  k_fc<<<500, 256, 0, stream>>>(ws + WS_HT, fc_W, fc_b, preds);
}